// Round 19
// baseline (107.789 us; speedup 1.0000x reference)
//
#include <hip/hip_runtime.h>
#include <hip/hip_bf16.h>

#define NSEG 200
#define STRENGTH 1e-3f
#define NFB 16384                   // fine bins per segment
#define FSCALE (16384.0f / 12.0f)
#define BT 1024                     // threads per k_hist/k_seg block
#define SPLIT 5                     // windows (partitions) per segment
#define WINCAP 9728                 // max window slots
#define SR 14                       // stage records per thread (1 head + 12 vec + 1 tail)
#define PSTRIDE (NFB + 8)           // u16 per segment in global pfx table
#define PCH 8192                    // elements per k_part chunk
#define SLICE_E 8200                // LDS pfx slice capacity (entries)

__device__ __forceinline__ int fbin_of(float v) {
    float t = (v + 6.0f) * FSCALE;
    int b = (int)floorf(t);
    return b < 0 ? 0 : (b > NFB - 1 ? NFB - 1 : b);
}

// ---- 1. per-segment: bounds + 2-copy fine hist + prefix -> pfxg; quantile bounds ----
__global__ void __launch_bounds__(BT)
k_hist(const float* __restrict__ x, const int* __restrict__ seg,
       int* __restrict__ seg_starts, float* __restrict__ segSums,
       unsigned* __restrict__ gcur, unsigned short* __restrict__ pfxg,
       int* __restrict__ Bg, int* __restrict__ Bpos, int N) {
    __shared__ unsigned hw[NFB];        // 64 KB: TWO copies of 8192 packed-u16 words
    __shared__ unsigned wsum[16];
    __shared__ int sh2[3];
    int s = blockIdx.x;
    int t = threadIdx.x;
    int copy = ((t >> 6) & 1) * (NFB / 2);   // even waves copy A, odd copy B
    if (t <= 1) {
        int key = s + t;
        int lo = 0, hi = N;
        while (lo < hi) { int mid = (lo + hi) >> 1; if (seg[mid] < key) lo = mid + 1; else hi = mid; }
        sh2[t] = lo;
    }
    if (t < 8) gcur[s * 8 + t] = 0u;
    if (t == 2) segSums[s] = 0.f;
    for (int k = t; k < NFB; k += BT) hw[k] = 0;
    __syncthreads();
    int st = sh2[0], en = sh2[1];
    if (t == 3) { seg_starts[s] = st; if (s == NSEG - 1) seg_starts[NSEG] = N; }
    int n = en - st;
    const float* xs = x + st;
    if (n > 0) {
        int head = min(n, (int)((4 - (st & 3)) & 3));
        for (int k = t; k < head; k += BT) { int f = fbin_of(xs[k]); atomicAdd(&hw[copy + (f >> 1)], 1u << ((f & 1) * 16)); }
        int nv = (n - head) >> 2;
        const float4* xs4 = (const float4*)(xs + head);
        for (int j = t; j < nv; j += BT) {
            float4 v = xs4[j];
            int f0 = fbin_of(v.x), f1 = fbin_of(v.y), f2 = fbin_of(v.z), f3 = fbin_of(v.w);
            atomicAdd(&hw[copy + (f0 >> 1)], 1u << ((f0 & 1) * 16));
            atomicAdd(&hw[copy + (f1 >> 1)], 1u << ((f1 & 1) * 16));
            atomicAdd(&hw[copy + (f2 >> 1)], 1u << ((f2 & 1) * 16));
            atomicAdd(&hw[copy + (f3 >> 1)], 1u << ((f3 & 1) * 16));
        }
        for (int k = head + nv * 4 + t; k < n; k += BT) { int f = fbin_of(xs[k]); atomicAdd(&hw[copy + (f >> 1)], 1u << ((f & 1) * 16)); }
    }
    __syncthreads();
    // exclusive prefix over 16384 bins (merge both copies); thread owns 8 words
    unsigned wv[8]; unsigned run = 0;
    #pragma unroll
    for (int i = 0; i < 8; ++i) {
        unsigned w = hw[t * 8 + i] + hw[NFB / 2 + t * 8 + i];   // field-wise add, no carry (sums <= n)
        unsigned c0 = w & 0xffffu, c1 = w >> 16;
        wv[i] = run | ((run + c0) << 16);
        run += c0 + c1;
    }
    unsigned incl = run;
    for (int off = 1; off < 64; off <<= 1) {
        unsigned nv2 = __shfl_up(incl, off, 64);
        if ((t & 63) >= off) incl += nv2;
    }
    if ((t & 63) == 63) wsum[t >> 6] = incl;
    __syncthreads();
    unsigned wb = 0; int myw = t >> 6;
    #pragma unroll
    for (int j = 0; j < 16; ++j) wb += (j < myw) ? wsum[j] : 0u;
    unsigned base = wb + incl - run;
    unsigned bb = base | (base << 16);
    unsigned short* pp = pfxg + (size_t)s * PSTRIDE;
    #pragma unroll
    for (int i = 0; i < 8; ++i) {
        unsigned pw = wv[i] + bb;
        hw[t * 8 + i] = pw;                       // copy-A region holds packed prefix
        ((unsigned*)pp)[t * 8 + i] = pw;
    }
    if (t == BT - 1) { pp[NFB] = (unsigned short)(base + run); sh2[2] = (int)(base + run); }
    __syncthreads();
    int nsh = sh2[2];
    if (t == 0) { Bg[s * 8 + 0] = 0; Bg[s * 8 + SPLIT] = NFB; Bpos[s * 8 + 0] = 0; Bpos[s * 8 + SPLIT] = nsh; }
    if (t >= 1 && t < SPLIT) {
        int target = (int)(((long)t * nsh) / SPLIT);
        int lo = 0, hi = NFB - 1;
        while (lo < hi) {
            int mid = (lo + hi) >> 1;
            int pv = (int)((hw[(mid + 1) >> 1] >> (((mid + 1) & 1) * 16)) & 0xffffu);
            if (pv > target) hi = mid; else lo = mid + 1;
        }
        Bg[s * 8 + t] = lo;
        Bpos[s * 8 + t] = (int)((hw[lo >> 1] >> ((lo & 1) * 16)) & 0xffffu);
    }
}

// ---- 2. 5-way partition scatter: per-thread packed-u64 counting, NO LDS atomics ----
__global__ void __launch_bounds__(1024)
k_part(const float* __restrict__ x, const int* __restrict__ seg_starts,
       const int* __restrict__ Bg, const int* __restrict__ Bpos,
       unsigned* __restrict__ gcur, float* __restrict__ part, int N) {
    __shared__ int sst[NSEG + 1];
    __shared__ unsigned long long wtA[16], wtB[16];   // per-wave inclusive totals
    __shared__ unsigned short wbase[16][10];          // cross-wave exclusive base per sp
    __shared__ int gb[10];
    __shared__ int sB[8];
    int t = threadIdx.x;
    int lane = t & 63, wid = t >> 6;
    for (int k = t; k < NSEG + 1; k += 1024) sst[k] = seg_starts[k];
    __syncthreads();
    int base = blockIdx.x * PCH;
    if (base >= N) return;
    int lo = 0, hi = NSEG - 1;
    while (lo < hi) { int mid = (lo + hi) >> 1; if (base < sst[mid + 1]) hi = mid; else lo = mid + 1; }
    int s0 = lo, bnd = sst[s0 + 1];
    if (t < 4) sB[t] = Bg[s0 * 8 + 1 + t];
    else if (t < 8) sB[t] = (s0 + 1 < NSEG) ? Bg[(s0 + 1) * 8 + 1 + (t - 4)] : 0x7fffffff;
    __syncthreads();
    // pass 1: classify, count in packed u64 fields (A: sp 0-4, B: sp 5-9; 12-bit fields)
    float vv[8]; unsigned spk = 0;
    unsigned long long A = 0, B = 0;
    const float4* x4 = (const float4*)(x + base);
    #pragma unroll
    for (int it = 0; it < 2; ++it) {
        int j = it * 1024 + t;
        int gi = base + j * 4;
        float4 v4 = (gi + 3 < N) ? x4[j] : make_float4(0.f, 0.f, 0.f, 0.f);
        #pragma unroll
        for (int e = 0; e < 4; ++e) {
            int i = it * 4 + e;
            float v = (e == 0) ? v4.x : (e == 1) ? v4.y : (e == 2) ? v4.z : v4.w;
            vv[i] = v;
            int g = gi + e;
            unsigned sp = 15u;
            if (g < N) {
                int off = (g >= bnd) ? 4 : 0;
                int f = fbin_of(v);
                int p = (f >= sB[off]) + (f >= sB[off + 1]) + (f >= sB[off + 2]) + (f >= sB[off + 3]);
                sp = (unsigned)((off >> 2) * 5 + p);
                if (sp < 5u) A += 1ull << (12 * sp);
                else B += 1ull << (12 * (sp - 5));
            }
            spk |= sp << (i * 4);
        }
    }
    // wave inclusive scan of packed counters
    unsigned long long iA = A, iB = B;
    #pragma unroll
    for (int off = 1; off < 64; off <<= 1) {
        unsigned long long uA = __shfl_up(iA, off, 64);
        unsigned long long uB = __shfl_up(iB, off, 64);
        if (lane >= off) { iA += uA; iB += uB; }
    }
    if (lane == 63) { wtA[wid] = iA; wtB[wid] = iB; }
    unsigned long long eA = iA - A, eB = iB - B;     // lane-exclusive (fields <= 512)
    __syncthreads();
    if (t < 160) {
        int w = t / 10, sp = t % 10;
        unsigned acc = 0;
        for (int w2 = 0; w2 < w; ++w2)
            acc += (unsigned)(((sp < 5) ? (wtA[w2] >> (12 * sp)) : (wtB[w2] >> (12 * (sp - 5)))) & 0xfffull);
        wbase[w][sp] = (unsigned short)acc;
    }
    __syncthreads();
    if (t < 10) {
        int sp = t;
        unsigned tot = (unsigned)wbase[15][sp] +
            (unsigned)(((sp < 5) ? (wtA[15] >> (12 * sp)) : (wtB[15] >> (12 * (sp - 5)))) & 0xfffull);
        int s = s0 + (sp >= 5);
        int p = (sp >= 5) ? sp - 5 : sp;
        int rsv = 0;
        if (tot > 0 && s < NSEG) rsv = (int)atomicAdd(&gcur[s * 8 + p], tot);
        gb[sp] = (s < NSEG) ? (sst[s] + Bpos[s * 8 + p] + rsv) : 0;
    }
    __syncthreads();
    // pass 2: place
    unsigned long long cA = 0, cB = 0;
    #pragma unroll
    for (int i = 0; i < 8; ++i) {
        unsigned sp = (spk >> (i * 4)) & 15u;
        if (sp < 10u) {
            unsigned fld;
            if (sp < 5u) { fld = (unsigned)(((eA + cA) >> (12 * sp)) & 0xfffull); cA += 1ull << (12 * sp); }
            else { fld = (unsigned)(((eB + cB) >> (12 * (sp - 5))) & 0xfffull); cB += 1ull << (12 * (sp - 5)); }
            int local = (int)wbase[wid][sp] + (int)fld;
            part[gb[sp] + local] = vv[i];
        }
    }
}

// ---- 3. per-(segment,window): stage (record own) -> rank own -> in-place sort -> diff ----
// s = bid % NSEG keeps all 5 blocks of a segment on one XCD (NSEG % 8 == 0).
__global__ void __launch_bounds__(BT)
k_seg(const float* __restrict__ part, const float* __restrict__ y,
      const int* __restrict__ seg_starts, const unsigned short* __restrict__ pfxg,
      const int* __restrict__ Bg, float* __restrict__ segSums) {
    __shared__ unsigned short slice[SLICE_E];          // 16400 B: pfx[Fa..Fb]
    __shared__ unsigned cur[2056];                     // 8224 B: packed byte cursors
    __shared__ __align__(16) float win[WINCAP + 4];    // 38928 B
    __shared__ float warr[16];
    int s = blockIdx.x % NSEG;
    int p = blockIdx.x / NSEG;
    int t = threadIdx.x;
    int st = seg_starts[s], en = seg_starts[s + 1];
    int n = en - st;
    if (n <= 0) return;
    const unsigned short* pp = pfxg + (size_t)s * PSTRIDE;
    int Fa = Bg[s * 8 + p], Fb = Bg[s * 8 + p + 1];
    int spanc = Fb - Fa;
    int w0 = pp[Fa], w1 = pp[Fb];
    int wsz = w1 - w0;
    if (wsz <= 0) return;
    const float* ps = part + st + w0;
    bool sliced = (spanc + 1) <= SLICE_E;

    float rv[SR]; unsigned rk[SR];
    #pragma unroll
    for (int r = 0; r < SR; ++r) rk[r] = 0xffffffffu;

    if (sliced) {
        for (int k = t; k <= spanc; k += BT) slice[k] = pp[Fa + k];
        for (int k = t; k < ((spanc + 4) >> 2); k += BT) cur[k] = 0u;
        __syncthreads();
        int head = min(wsz, (int)((4 - ((st + w0) & 3)) & 3));
        if (t < head) {                                  // record slot 0
            float v = ps[t];
            int i = fbin_of(v) - Fa;
            unsigned shf = (i & 3) * 8;
            unsigned old = atomicAdd(&cur[i >> 2], 1u << shf);
            int slot = (int)slice[i] - w0 + (int)((old >> shf) & 0xFFu);
            win[slot] = v;
            rv[0] = v; rk[0] = ((unsigned)i << 14) | (unsigned)slot;
        }
        int nv = (wsz - head) >> 2;
        const float4* ps4 = (const float4*)(ps + head);
        #pragma unroll
        for (int g = 0; g < 3; ++g) {                    // record slots 1..12
            int j = g * BT + t;
            if (j < nv) {
                float4 v4 = ps4[j];
                #pragma unroll
                for (int e = 0; e < 4; ++e) {
                    float v = (e == 0) ? v4.x : (e == 1) ? v4.y : (e == 2) ? v4.z : v4.w;
                    int i = fbin_of(v) - Fa;
                    unsigned shf = (i & 3) * 8;
                    unsigned old = atomicAdd(&cur[i >> 2], 1u << shf);
                    int slot = (int)slice[i] - w0 + (int)((old >> shf) & 0xFFu);
                    win[slot] = v;
                    rv[1 + g * 4 + e] = v;
                    rk[1 + g * 4 + e] = ((unsigned)i << 14) | (unsigned)slot;
                }
            }
        }
        int k2 = head + nv * 4 + t;
        if (k2 < wsz) {                                  // record slot 13
            float v = ps[k2];
            int i = fbin_of(v) - Fa;
            unsigned shf = (i & 3) * 8;
            unsigned old = atomicAdd(&cur[i >> 2], 1u << shf);
            int slot = (int)slice[i] - w0 + (int)((old >> shf) & 0xFFu);
            win[slot] = v;
            rv[13] = v; rk[13] = ((unsigned)i << 14) | (unsigned)slot;
        }
        if (t < 4) win[wsz + t] = __builtin_inff();
        __syncthreads();
        // rank own staged elements (monotone bins: under-read strictly smaller ->
        // cancelled; over-read strictly larger / INF pad -> adds 0). Ties by slot.
        #pragma unroll
        for (int r = 0; r < SR; ++r) {
            if (rk[r] != 0xffffffffu) {
                float v = rv[r];
                int i = (int)(rk[r] >> 14);
                int slot = (int)(rk[r] & 0x3fffu);
                int ls = (int)slice[i] - w0, le = (int)slice[i + 1] - w0;
                int a = ls & ~3;
                int cnt = a - ls;
                for (int j = a; j < le; j += 4) {
                    float4 qv = *(const float4*)&win[j];
                    cnt += (qv.x < v) + ((qv.x == v) & (j + 0 < slot));
                    cnt += (qv.y < v) + ((qv.y == v) & (j + 1 < slot));
                    cnt += (qv.z < v) + ((qv.z == v) & (j + 2 < slot));
                    cnt += (qv.w < v) + ((qv.w == v) & (j + 3 < slot));
                }
                rk[r] = (unsigned)(ls + cnt);            // local sorted index
            }
        }
    } else {
        // fallback (span exceeds slice cap — degenerate only): linear stage,
        // whole-window rank of own elements (window is bin-aligned).
        #pragma unroll
        for (int g = 0; g < 10; ++g) {
            int k = g * BT + t;
            if (k < wsz) { float v = ps[k]; win[k] = v; rv[g] = v; rk[g] = (unsigned)k; }
        }
        if (t < 4) win[wsz + t] = __builtin_inff();
        __syncthreads();
        #pragma unroll
        for (int g = 0; g < 10; ++g) {
            if (rk[g] != 0xffffffffu) {
                float v = rv[g];
                int slot = (int)rk[g];
                int cnt = 0;
                for (int j = 0; j < wsz; j += 4) {
                    float4 qv = *(const float4*)&win[j];
                    cnt += (qv.x < v) + ((qv.x == v) & (j + 0 < slot));
                    cnt += (qv.y < v) + ((qv.y == v) & (j + 1 < slot));
                    cnt += (qv.z < v) + ((qv.z == v) & (j + 2 < slot));
                    cnt += (qv.w < v) + ((qv.w == v) & (j + 3 < slot));
                }
                rk[g] = (unsigned)cnt;
            }
        }
    }
    __syncthreads();
    // in-place sorted rewrite (ranks form a bijection on [0,wsz))
    #pragma unroll
    for (int r = 0; r < SR; ++r) {
        if (rk[r] != 0xffffffffu) win[rk[r]] = rv[r];
    }
    __syncthreads();
    // coalesced diff against y
    float acc = 0.f;
    const float* yw = y + st + w0;
    int head2 = min(wsz, (int)((4 - ((st + w0) & 3)) & 3));
    for (int k = t; k < head2; k += BT) acc += fabsf(win[k] - yw[k]);
    int nv2 = (wsz - head2) >> 2;
    const float4* yw4 = (const float4*)(yw + head2);
    for (int j = t; j < nv2; j += BT) {
        float4 yv = yw4[j];
        int k = head2 + j * 4;
        acc += fabsf(win[k + 0] - yv.x);
        acc += fabsf(win[k + 1] - yv.y);
        acc += fabsf(win[k + 2] - yv.z);
        acc += fabsf(win[k + 3] - yv.w);
    }
    for (int k = head2 + nv2 * 4 + t; k < wsz; k += BT) acc += fabsf(win[k] - yw[k]);

    for (int off = 32; off > 0; off >>= 1) acc += __shfl_xor(acc, off, 64);
    if ((t & 63) == 0) warr[t >> 6] = acc;
    __syncthreads();
    if (t == 0) {
        float tot = 0.f;
        #pragma unroll
        for (int j = 0; j < 16; ++j) tot += warr[j];
        if (tot != 0.f) atomicAdd(&segSums[s], tot);
    }
}

// ---- 4. finalize ----
__global__ void k_final(const float* __restrict__ segSums, const int* __restrict__ seg_starts,
                        float* __restrict__ out) {
    __shared__ float red[256];
    int t = threadIdx.x;
    float a = 0.f;
    for (int k = t; k < NSEG; k += 256) {
        float n = (float)(seg_starts[k + 1] - seg_starts[k]);
        a += segSums[k] / fmaxf(n, 1.0f);
    }
    red[t] = a;
    __syncthreads();
    for (int off = 128; off > 0; off >>= 1) {
        if (t < off) red[t] += red[t + off];
        __syncthreads();
    }
    if (t == 0) out[0] = red[0] * (1.0f / (float)NSEG) * STRENGTH;
}

extern "C" void kernel_launch(void* const* d_in, const int* in_sizes, int n_in,
                              void* d_out, int out_size, void* d_ws, size_t ws_size,
                              hipStream_t stream) {
    const float* x = (const float*)d_in[0];
    const float* y = (const float*)d_in[1];          // initial_sorted
    const int* seg = (const int*)d_in[2];            // segment_ids (sorted)
    int N = in_sizes[0];

    char* ws = (char*)d_ws;
    float* segSums    = (float*)ws;                          // 200 f32      @0
    int*   seg_starts = (int*)(ws + 800);                    // 201 i32      @800
    unsigned* gcur    = (unsigned*)(ws + 1616);              // 1600 u32     @1616
    int*   Bg         = (int*)(ws + 8016);                   // 1608 i32     @8016
    int*   Bpos       = (int*)(ws + 14448);                  // 1608 i32     @14448
    unsigned short* pfxg = (unsigned short*)(ws + 20880);    // 200*PSTRIDE u16
    float* part       = (float*)(ws + 20880 + (size_t)NSEG * PSTRIDE * 2 + 16);

    int nchunk = (N + PCH - 1) / PCH;

    k_hist<<<NSEG, BT, 0, stream>>>(x, seg, seg_starts, segSums, gcur, pfxg, Bg, Bpos, N);
    k_part<<<nchunk, 1024, 0, stream>>>(x, seg_starts, Bg, Bpos, gcur, part, N);
    k_seg<<<NSEG * SPLIT, BT, 0, stream>>>(part, y, seg_starts, pfxg, Bg, segSums);
    k_final<<<1, 256, 0, stream>>>(segSums, seg_starts, (float*)d_out);
}